// Round 3
// baseline (829.700 us; speedup 1.0000x reference)
//
#include <hip/hip_runtime.h>

#define HID 256
#define LAT 128
#define VOC 32000
#define NSTEP 128

// ---------------- fused encoder: two tree levels per launch ----------------
// Block b computes parent i = base+b: first its two children (level L), then
// itself (level L-1). Grandchildren are either leaf embeds or h rows.
__global__ void enc_level2(const float* __restrict__ embed, const int* __restrict__ values,
                           const float* __restrict__ Wpar, const float* __restrict__ bpar,
                           float* __restrict__ h, int base, int leafgc) {
    const int i = base + blockIdx.x;
    const int t = threadIdx.x;             // 0..255
    __shared__ __align__(16) float cat[768];
    __shared__ float hc[2][256];
    const float bv = bpar[t];
    const float4* wr = (const float4*)(Wpar + (size_t)t * 768);

    for (int s = 0; s < 2; s++) {
        const int c = 2 * i + 1 + s;
        cat[t] = embed[(size_t)values[c] * HID + t];
        const int g1 = 2 * c + 1, g2 = 2 * c + 2;
        if (leafgc) {
            cat[256 + t] = embed[(size_t)values[g1] * HID + t];
            cat[512 + t] = embed[(size_t)values[g2] * HID + t];
        } else {
            cat[256 + t] = h[(size_t)g1 * HID + t];
            cat[512 + t] = h[(size_t)g2 * HID + t];
        }
        __syncthreads();
        float acc = bv;
        const float4* cf = (const float4*)cat;
#pragma unroll 8
        for (int k = 0; k < 192; k++) {
            float4 w = wr[k], cc = cf[k];
            acc += w.x * cc.x + w.y * cc.y + w.z * cc.z + w.w * cc.w;
        }
        hc[s][t] = acc;
        h[(size_t)c * HID + t] = acc;
        __syncthreads();
    }
    cat[t] = embed[(size_t)values[i] * HID + t];
    cat[256 + t] = hc[0][t];
    cat[512 + t] = hc[1][t];
    __syncthreads();
    float acc = bv;
    const float4* cf = (const float4*)cat;
#pragma unroll 8
    for (int k = 0; k < 192; k++) {
        float4 w = wr[k], cc = cf[k];
        acc += w.x * cc.x + w.y * cc.y + w.z * cc.z + w.w * cc.w;
    }
    h[(size_t)i * HID + t] = acc;
}

// ---------------- root head: mu, logvar, z ----------------
__global__ void root_kernel(const float* __restrict__ h,
                            const float* __restrict__ Wmu, const float* __restrict__ bmu,
                            const float* __restrict__ Wlv, const float* __restrict__ blv,
                            const float* __restrict__ eps,
                            float* __restrict__ out, float* __restrict__ z) {
    const int t = threadIdx.x;             // 0..127
    __shared__ __align__(16) float root_s[256];
    root_s[t] = h[t];
    root_s[128 + t] = h[128 + t];
    __syncthreads();
    float am = bmu[t], al = blv[t];
    const float4* wm = (const float4*)(Wmu + (size_t)t * HID);
    const float4* wl = (const float4*)(Wlv + (size_t)t * HID);
    const float4* r4 = (const float4*)root_s;
#pragma unroll 8
    for (int k = 0; k < 64; k++) {
        float4 r = r4[k];
        float4 a = wm[k], b = wl[k];
        am += a.x * r.x + a.y * r.y + a.z * r.z + a.w * r.w;
        al += b.x * r.x + b.y * r.y + b.z * r.z + b.w * r.w;
    }
    out[(size_t)NSTEP * VOC + t] = am;
    out[(size_t)NSTEP * VOC + 128 + t] = al;
    z[t] = am + eps[t] * expf(0.5f * al);
}

// ---------------- precompute Wcomb = Wp_tail @ W2[1:], bcomb ----------------
__global__ void wcomb_kernel(const float* __restrict__ Wp, const float* __restrict__ W2,
                             const float* __restrict__ b2, const float* __restrict__ bp,
                             float* __restrict__ Wcomb, float* __restrict__ bcomb) {
    const int o = blockIdx.x;              // 0..255
    const int k = threadIdx.x;             // 0..255
    __shared__ float wpt_s[256];
    __shared__ float red_s[4];
    wpt_s[k] = Wp[(size_t)(VOC + o) * HID + k];
    __syncthreads();
    float acc = 0.f;
#pragma unroll 8
    for (int j = 0; j < 256; j++)
        acc += wpt_s[j] * W2[(size_t)(1 + j) * HID + k];
    Wcomb[(size_t)o * HID + k] = acc;
    // bcomb[o] = bp[VOC+o] + wpt . b2[1:]
    float p = wpt_s[k] * b2[1 + k];
    p += __shfl_xor(p, 1);  p += __shfl_xor(p, 2);  p += __shfl_xor(p, 4);
    p += __shfl_xor(p, 8);  p += __shfl_xor(p, 16); p += __shfl_xor(p, 32);
    if ((k & 63) == 0) red_s[k >> 6] = p;
    __syncthreads();
    if (k == 0) bcomb[o] = bp[VOC + o] + red_s[0] + red_s[1] + red_s[2] + red_s[3];
}

// ---------------- sequential decoder recurrence ----------------
// Register-blocked matvecs: matvec1 (256x128) R=2 outputs x C=32 k per thread,
// matvec2 (256x256) R=4 x C=32. LDS reads use per-output-group rotation so the
// weight registers are loaded pre-rotated to match. Partials reduced with
// __shfl_xor across the 4/8 k-chunk lanes. Branch scalar c0 computed by wave 0
// only; decision applied at the TOP of the next step (carried across barrier).
// Stack push is speculative/unconditional (target rows are dead on non-parent
// paths); row 64 is scratch for the forced-leaf sp==64 edge.
__global__ __launch_bounds__(512, 2)
void recur_kernel(const float* __restrict__ W1, const float* __restrict__ b1,
                  const float* __restrict__ W2, const float* __restrict__ b2,
                  const float* __restrict__ Wcomb, const float* __restrict__ bcomb,
                  const float* __restrict__ z,
                  float* __restrict__ Hrec, int* __restrict__ rowflag) {
    const int t = threadIdx.x;
    __shared__ __align__(16) float stack_s[65 * 128];   // 32.5 KB
    __shared__ __align__(16) float hmid_s[256];
    __shared__ float c0_s;

    const int og1 = t >> 2, kc1 = t & 3;   // matvec1: outputs {2og1,2og1+1}, k in [32kc1,32kc1+32)
    const int o1 = 2 * og1;
    const int og2 = t >> 3, kc2 = t & 7;   // matvec2: outputs [4og2,4og2+4), k in [32kc2,32kc2+32)
    const int o2 = 4 * og2;

    // pre-rotated resident weights
    float4 w1a[8], w1b[8];
#pragma unroll
    for (int j4 = 0; j4 < 8; j4++) {
        const int rot = (j4 + og1) & 7;
        w1a[j4] = *(const float4*)(W1 + (size_t)o1 * 128 + kc1 * 32 + rot * 4);
        w1b[j4] = *(const float4*)(W1 + (size_t)(o1 + 1) * 128 + kc1 * 32 + rot * 4);
    }
    float4 wc[4][8];
#pragma unroll
    for (int r = 0; r < 4; r++)
#pragma unroll
        for (int j4 = 0; j4 < 8; j4++) {
            const int rot = (j4 + og2) & 7;
            wc[r][j4] = *(const float4*)(Wcomb + (size_t)(o2 + r) * HID + kc2 * 32 + rot * 4);
        }
    const float b1a = b1[o1], b1b = b1[o1 + 1];
    const float4 bc4 = *(const float4*)(bcomb + o2);
    const float4 w2q = *(const float4*)(W2 + 4 * (t & 63));
    const float b20 = b2[0];

    if (t < 128) { stack_s[t] = z[t]; rowflag[t] = -1; }
    int sp = 1, op = 0;
    __syncthreads();

    for (int step = 0; step < NSTEP; step++) {
        // apply previous step's decision (c0_s written by wave 0 last step)
        if (step > 0) {
            const float c0 = c0_s + b20;
            const bool ap = sp > 0;
            const int par = (c0 > 0.f) && (sp <= 63) && ap;
            if (t == 0 && ap) rowflag[op] = par;
            if (ap) { sp = par ? sp + 1 : sp - 1; op++; }
        }
        const bool active = sp > 0;
        const int idx = active ? sp - 1 : 0;

        // ---- matvec1: hmid = lrelu(W1 @ node + b1) ----
        const float* np = stack_s + idx * 128 + kc1 * 32;
        float a0 = 0.f, a1 = 0.f;
#pragma unroll
        for (int j4 = 0; j4 < 8; j4++) {
            const float4 v = *(const float4*)(np + ((j4 + og1) & 7) * 4);
            a0 += w1a[j4].x * v.x + w1a[j4].y * v.y + w1a[j4].z * v.z + w1a[j4].w * v.w;
            a1 += w1b[j4].x * v.x + w1b[j4].y * v.y + w1b[j4].z * v.z + w1b[j4].w * v.w;
        }
        a0 += __shfl_xor(a0, 1); a0 += __shfl_xor(a0, 2);
        a1 += __shfl_xor(a1, 1); a1 += __shfl_xor(a1, 2);
        if (kc1 == 0) {
            float pa = a0 + b1a; pa = pa > 0.f ? pa : 0.2f * pa;
            float pb = a1 + b1b; pb = pb > 0.f ? pb : 0.2f * pb;
            *(float2*)(hmid_s + o1) = make_float2(pa, pb);
            if (active) *(float2*)(Hrec + (size_t)op * HID + o1) = make_float2(pa, pb);
        }
        __syncthreads();                               // b1: hmid visible

        // ---- c0 partial + reduce (wave 0 only) ----
        if (t < 64) {
            const float4 hv = *(const float4*)(hmid_s + 4 * t);
            float p = w2q.x * hv.x + w2q.y * hv.y + w2q.z * hv.z + w2q.w * hv.w;
            p += __shfl_xor(p, 1);  p += __shfl_xor(p, 2);  p += __shfl_xor(p, 4);
            p += __shfl_xor(p, 8);  p += __shfl_xor(p, 16); p += __shfl_xor(p, 32);
            if (t == 0) c0_s = p;
        }

        // ---- matvec2: push = Wcomb @ hmid + bcomb (speculative) ----
        const float* hp = hmid_s + kc2 * 32;
        float s0 = 0.f, s1 = 0.f, s2 = 0.f, s3 = 0.f;
#pragma unroll
        for (int j4 = 0; j4 < 8; j4++) {
            const float4 v = *(const float4*)(hp + ((j4 + og2) & 7) * 4);
            s0 += wc[0][j4].x * v.x + wc[0][j4].y * v.y + wc[0][j4].z * v.z + wc[0][j4].w * v.w;
            s1 += wc[1][j4].x * v.x + wc[1][j4].y * v.y + wc[1][j4].z * v.z + wc[1][j4].w * v.w;
            s2 += wc[2][j4].x * v.x + wc[2][j4].y * v.y + wc[2][j4].z * v.z + wc[2][j4].w * v.w;
            s3 += wc[3][j4].x * v.x + wc[3][j4].y * v.y + wc[3][j4].z * v.z + wc[3][j4].w * v.w;
        }
        s0 += __shfl_xor(s0, 1); s0 += __shfl_xor(s0, 2); s0 += __shfl_xor(s0, 4);
        s1 += __shfl_xor(s1, 1); s1 += __shfl_xor(s1, 2); s1 += __shfl_xor(s1, 4);
        s2 += __shfl_xor(s2, 1); s2 += __shfl_xor(s2, 2); s2 += __shfl_xor(s2, 4);
        s3 += __shfl_xor(s3, 1); s3 += __shfl_xor(s3, 2); s3 += __shfl_xor(s3, 4);
        if (kc2 == 0) {
            const int row = idx + (og2 >> 5);          // ll -> idx, rl -> idx+1
            const int col = (4 * og2) & 127;
            *(float4*)(stack_s + row * 128 + col) =
                make_float4(s0 + bc4.x, s1 + bc4.y, s2 + bc4.z, s3 + bc4.w);
        }
        __syncthreads();                               // b2: stack + c0_s visible
    }
    // finalize last step's rowflag
    {
        const float c0 = c0_s + b20;
        const bool ap = sp > 0;
        const int par = (c0 > 0.f) && (sp <= 63) && ap;
        if (t == 0 && ap) rowflag[op] = par;
    }
}

// ---------------- Co1 = Hrec @ W2[1:].T + b2[1:] ----------------
__global__ void co1_kernel(const float* __restrict__ Hrec, const float* __restrict__ W2,
                           const float* __restrict__ b2, float* __restrict__ Co1) {
    const int r = blockIdx.x;              // 0..127
    const int c = threadIdx.x;             // 0..255
    __shared__ __align__(16) float hs[256];
    hs[c] = Hrec[(size_t)r * HID + c];
    __syncthreads();
    float acc = b2[1 + c];
    const float4* w = (const float4*)(W2 + (size_t)(1 + c) * HID);
    const float4* h4 = (const float4*)hs;
#pragma unroll 8
    for (int k = 0; k < 64; k++) {
        float4 a = w[k], b = h4[k];
        acc += a.x * b.x + a.y * b.y + a.z * b.z + a.w * b.w;
    }
    Co1[(size_t)r * HID + c] = acc;
}

// ---------------- build compacted row lists (global, for scalar loads) ----------------
__global__ void compact_kernel(const int* __restrict__ rowflag,
                               int* __restrict__ listc, int* __restrict__ counts) {
    const int t = threadIdx.x;             // 128 threads
    __shared__ int rf[128];
    rf[t] = rowflag[t];
    __syncthreads();
    if (t == 0) {
        int n0 = 0, n1 = 0;
        for (int r = 0; r < 128; r++) {
            if (rf[r] == 0) listc[n0++] = r;
            else if (rf[r] == 1) listc[128 + n1++] = r;
        }
        counts[0] = n0; counts[1] = n1;
    }
}

// ---------------- zero unused out rows ----------------
__global__ void zero_rows(const int* __restrict__ rowflag, float* __restrict__ out) {
    const int r = blockIdx.x;
    if (rowflag[r] != -1) return;
    for (int q = threadIdx.x; q < VOC; q += 256) out[(size_t)r * VOC + q] = 0.f;
}

// ---------------- batched vocab matvecs (no LDS: Co1 via uniform scalar loads) ----------------
__global__ __launch_bounds__(256)
void value_kernel(const float* __restrict__ Co1, const int* __restrict__ listc,
                  const int* __restrict__ counts,
                  const float* __restrict__ Wl, const float* __restrict__ bl,
                  const float* __restrict__ Wp, const float* __restrict__ bp,
                  float* __restrict__ out) {
    const int m = blockIdx.y;              // 0 = leaf (Wl), 1 = parent (Wp)
    const int t = threadIdx.x;
    const int v = blockIdx.x * 256 + t;    // 0..31999
    const float* Wx = m ? Wp : Wl;
    const float* bx = m ? bp : bl;
    const int n = counts[m];               // uniform -> SGPR
    const float bv = bx[v];
    const float4* w4 = (const float4*)(Wx + (size_t)v * HID);

    for (int rc = 0; rc < n; rc += 32) {
        int rowid[32];
#pragma unroll
        for (int rr = 0; rr < 32; rr++) {
            const int rs = rc + rr;
            rowid[rr] = listc[m * 128 + (rs < n ? rs : 0)];   // uniform -> SGPR
        }
        float acc[32];
#pragma unroll
        for (int rr = 0; rr < 32; rr++) acc[rr] = 0.f;

        for (int kc = 0; kc < 4; kc++) {
            float4 w[16];
#pragma unroll
            for (int i = 0; i < 16; i++) w[i] = w4[kc * 16 + i];
#pragma unroll
            for (int rr = 0; rr < 32; rr++) {
                const float4* c4 = (const float4*)(Co1 + (size_t)rowid[rr] * HID + kc * 64);
                float s = 0.f;
#pragma unroll
                for (int i = 0; i < 16; i++) {
                    const float4 c = c4[i];                   // uniform -> SGPR operands
                    s += w[i].x * c.x + w[i].y * c.y + w[i].z * c.z + w[i].w * c.w;
                }
                acc[rr] += s;
            }
        }
        const int nr = (n - rc < 32) ? (n - rc) : 32;
        for (int rr = 0; rr < nr; rr++)
            out[(size_t)rowid[rr] * VOC + v] = acc[rr] + bv;
    }
}

extern "C" void kernel_launch(void* const* d_in, const int* in_sizes, int n_in,
                              void* d_out, int out_size, void* d_ws, size_t ws_size,
                              hipStream_t stream) {
    const float* embed = (const float*)d_in[0];
    const float* Wpar  = (const float*)d_in[1];
    const float* bpar  = (const float*)d_in[2];
    const float* Wmu   = (const float*)d_in[3];
    const float* bmu   = (const float*)d_in[4];
    const float* Wlv   = (const float*)d_in[5];
    const float* blv   = (const float*)d_in[6];
    const float* W1    = (const float*)d_in[7];
    const float* b1    = (const float*)d_in[8];
    const float* W2    = (const float*)d_in[9];
    const float* b2    = (const float*)d_in[10];
    const float* Wl    = (const float*)d_in[11];
    const float* bl    = (const float*)d_in[12];
    const float* Wp    = (const float*)d_in[13];
    const float* bp    = (const float*)d_in[14];
    const float* eps   = (const float*)d_in[15];
    const int*  values = (const int*)d_in[16];

    float* ws = (float*)d_ws;
    float* h      = ws;                    // 511*256 (children rows written too)
    float* z      = ws + 131072;           // 128
    float* Wcomb  = ws + 131200;           // 65536
    float* bcomb  = ws + 196736;           // 256
    float* Hrec   = ws + 196992;           // 128*256 = 32768
    float* Co1    = ws + 229760;           // 32768
    int*   rowflag = (int*)(ws + 262528);  // 128
    int*   listc   = (int*)(ws + 262656);  // 256
    int*   counts  = (int*)(ws + 262912);  // 2
    float* out = (float*)d_out;

    // collapsed push-weights (independent of encoder)
    wcomb_kernel<<<256, 256, 0, stream>>>(Wp, W2, b2, bp, Wcomb, bcomb);

    // encoder: levels (7,6), (5,4), (3,2), (1,0)
    enc_level2<<<64, 256, 0, stream>>>(embed, values, Wpar, bpar, h, 63, 1);
    enc_level2<<<16, 256, 0, stream>>>(embed, values, Wpar, bpar, h, 15, 0);
    enc_level2<<< 4, 256, 0, stream>>>(embed, values, Wpar, bpar, h,  3, 0);
    enc_level2<<< 1, 256, 0, stream>>>(embed, values, Wpar, bpar, h,  0, 0);

    root_kernel<<<1, 128, 0, stream>>>(h, Wmu, bmu, Wlv, blv, eps, out, z);

    recur_kernel<<<1, 512, 0, stream>>>(W1, b1, W2, b2, Wcomb, bcomb, z, Hrec, rowflag);

    compact_kernel<<<1, 128, 0, stream>>>(rowflag, listc, counts);
    co1_kernel<<<128, 256, 0, stream>>>(Hrec, W2, b2, Co1);
    zero_rows<<<128, 256, 0, stream>>>(rowflag, out);
    value_kernel<<<dim3(125, 2), 256, 0, stream>>>(Co1, listc, counts, Wl, bl, Wp, bp, out);
}

// Round 4
// 678.490 us; speedup vs baseline: 1.2229x; 1.2229x over previous
//
#include <hip/hip_runtime.h>

#define HID 256
#define LAT 128
#define VOC 32000
#define NSTEP 128

// ---------------- fused encoder: two tree levels per launch ----------------
__global__ void enc_level2(const float* __restrict__ embed, const int* __restrict__ values,
                           const float* __restrict__ Wpar, const float* __restrict__ bpar,
                           float* __restrict__ h, int base, int leafgc) {
    const int i = base + blockIdx.x;
    const int t = threadIdx.x;             // 0..255
    __shared__ __align__(16) float cat[768];
    __shared__ float hc[2][256];
    const float bv = bpar[t];
    const float4* wr = (const float4*)(Wpar + (size_t)t * 768);

    for (int s = 0; s < 2; s++) {
        const int c = 2 * i + 1 + s;
        cat[t] = embed[(size_t)values[c] * HID + t];
        const int g1 = 2 * c + 1, g2 = 2 * c + 2;
        if (leafgc) {
            cat[256 + t] = embed[(size_t)values[g1] * HID + t];
            cat[512 + t] = embed[(size_t)values[g2] * HID + t];
        } else {
            cat[256 + t] = h[(size_t)g1 * HID + t];
            cat[512 + t] = h[(size_t)g2 * HID + t];
        }
        __syncthreads();
        float acc = bv;
        const float4* cf = (const float4*)cat;
#pragma unroll 8
        for (int k = 0; k < 192; k++) {
            float4 w = wr[k], cc = cf[k];
            acc += w.x * cc.x + w.y * cc.y + w.z * cc.z + w.w * cc.w;
        }
        hc[s][t] = acc;
        h[(size_t)c * HID + t] = acc;
        __syncthreads();
    }
    cat[t] = embed[(size_t)values[i] * HID + t];
    cat[256 + t] = hc[0][t];
    cat[512 + t] = hc[1][t];
    __syncthreads();
    float acc = bv;
    const float4* cf = (const float4*)cat;
#pragma unroll 8
    for (int k = 0; k < 192; k++) {
        float4 w = wr[k], cc = cf[k];
        acc += w.x * cc.x + w.y * cc.y + w.z * cc.z + w.w * cc.w;
    }
    h[(size_t)i * HID + t] = acc;
}

// ---------------- tail: nodes 14..0 (levels 3..0) + root head, one block ----------------
__global__ void enc_tail(const float* __restrict__ embed, const int* __restrict__ values,
                         const float* __restrict__ Wpar, const float* __restrict__ bpar,
                         const float* __restrict__ h,
                         const float* __restrict__ Wmu, const float* __restrict__ bmu,
                         const float* __restrict__ Wlv, const float* __restrict__ blv,
                         const float* __restrict__ eps,
                         float* __restrict__ out, float* __restrict__ z) {
    const int t = threadIdx.x;             // 0..255
    __shared__ __align__(16) float hloc[15][256];
    __shared__ __align__(16) float cat[768];
    const float bv = bpar[t];
    const float4* wr = (const float4*)(Wpar + (size_t)t * 768);

    for (int i = 14; i >= 0; i--) {
        cat[t] = embed[(size_t)values[i] * HID + t];
        const int c1 = 2 * i + 1, c2 = 2 * i + 2;
        cat[256 + t] = (c1 <= 14) ? hloc[c1][t] : h[(size_t)c1 * HID + t];
        cat[512 + t] = (c2 <= 14) ? hloc[c2][t] : h[(size_t)c2 * HID + t];
        __syncthreads();
        float acc = bv;
        const float4* cf = (const float4*)cat;
#pragma unroll 8
        for (int k = 0; k < 192; k++) {
            float4 w = wr[k], cc = cf[k];
            acc += w.x * cc.x + w.y * cc.y + w.z * cc.z + w.w * cc.w;
        }
        hloc[i][t] = acc;
        __syncthreads();
    }
    // root head: mu, logvar, z from hloc[0]
    if (t < 128) {
        float am = bmu[t], al = blv[t];
        const float4* wm = (const float4*)(Wmu + (size_t)t * HID);
        const float4* wl = (const float4*)(Wlv + (size_t)t * HID);
        const float4* r4 = (const float4*)hloc[0];
#pragma unroll 8
        for (int k = 0; k < 64; k++) {
            float4 r = r4[k];
            float4 a = wm[k], b = wl[k];
            am += a.x * r.x + a.y * r.y + a.z * r.z + a.w * r.w;
            al += b.x * r.x + b.y * r.y + b.z * r.z + b.w * r.w;
        }
        out[(size_t)NSTEP * VOC + t] = am;
        out[(size_t)NSTEP * VOC + 128 + t] = al;
        z[t] = am + eps[t] * expf(0.5f * al);
    }
}

// ---------------- precompute Wcomb = Wp_tail @ W2[1:], bcomb ----------------
__global__ void wcomb_kernel(const float* __restrict__ Wp, const float* __restrict__ W2,
                             const float* __restrict__ b2, const float* __restrict__ bp,
                             float* __restrict__ Wcomb, float* __restrict__ bcomb) {
    const int o = blockIdx.x;              // 0..255
    const int k = threadIdx.x;             // 0..255
    __shared__ float wpt_s[256];
    __shared__ float red_s[4];
    wpt_s[k] = Wp[(size_t)(VOC + o) * HID + k];
    __syncthreads();
    float acc = 0.f;
#pragma unroll 8
    for (int j = 0; j < 256; j++)
        acc += wpt_s[j] * W2[(size_t)(1 + j) * HID + k];
    Wcomb[(size_t)o * HID + k] = acc;
    float p = wpt_s[k] * b2[1 + k];
    p += __shfl_xor(p, 1);  p += __shfl_xor(p, 2);  p += __shfl_xor(p, 4);
    p += __shfl_xor(p, 8);  p += __shfl_xor(p, 16); p += __shfl_xor(p, 32);
    if ((k & 63) == 0) red_s[k >> 6] = p;
    __syncthreads();
    if (k == 0) bcomb[o] = bp[VOC + o] + red_s[0] + red_s[1] + red_s[2] + red_s[3];
}

// ---------------- sequential decoder recurrence ----------------
// Thread t: output o = t>>1 for BOTH matvecs, k-half hk = t&1. Weights loaded
// once into registers before the loop. The weight pointers are intentionally
// NOT __restrict and a global Hrec store occurs every iteration: the compiler
// cannot prove no-alias, so it cannot rematerialize (re-load) the weights
// inside the loop -> they stay register-resident (ask ~= 225 VGPR < 256 cap).
// mv2 runs only on parent steps (block-uniform branch); c0 is computed in-step
// redundantly by every wave (deterministic -> identical across waves).
// Early break when sp==0 (remaining reference steps are no-ops).
__global__ __launch_bounds__(512, 2)
void recur_kernel(const float* W1, const float* b1,
                  const float* W2, const float* b2,
                  const float* Wcomb, const float* bcomb,
                  const float* z,
                  float* Hrec, int* rowflag) {
    const int t = threadIdx.x;
    const int o = t >> 1;                  // 0..255
    const int hk = t & 1;
    __shared__ __align__(16) float stack_s[64 * 128];   // 32 KB
    __shared__ __align__(16) float hmid_s[256];

    // resident weights
    float4 w1r[16];
#pragma unroll
    for (int j = 0; j < 16; j++)
        w1r[j] = *(const float4*)(W1 + (size_t)o * 128 + hk * 64 + 4 * j);
    float4 wcr[32];
#pragma unroll
    for (int j = 0; j < 32; j++)
        wcr[j] = *(const float4*)(Wcomb + (size_t)o * 256 + hk * 128 + 4 * j);

    const float b1o = b1[o];
    const float bco = bcomb[o];
    const float b20 = b2[0];
    const int l64 = t & 63;
    const float4 w2q = *(const float4*)(W2 + 4 * l64);

    if (t < 128) stack_s[t] = z[t];
    int sp = 1, op = 0;
    unsigned long long pm0 = 0ULL, pm1 = 0ULL;
    __syncthreads();

    for (int step = 0; step < NSTEP; step++) {
        if (sp <= 0) break;
        const int idx = sp - 1;

        // mv1: hmid = lrelu(W1 @ node + b1), split-K=2 (even/odd lanes)
        const float* np = stack_s + idx * 128 + hk * 64;
        float a = 0.f;
#pragma unroll
        for (int j = 0; j < 16; j++) {
            const float4 v = *(const float4*)(np + 4 * j);
            a += w1r[j].x * v.x + w1r[j].y * v.y + w1r[j].z * v.z + w1r[j].w * v.w;
        }
        a += __shfl_xor(a, 1);
        if (hk == 0) {
            float pre = a + b1o;
            pre = pre > 0.f ? pre : 0.2f * pre;
            hmid_s[o] = pre;
            Hrec[(size_t)op * HID + o] = pre;   // remat-blocker + record
        }
        __syncthreads();                         // b1: hmid visible

        // c0 decision dot: every wave redundantly (identical result)
        const float4 hq = *(const float4*)(hmid_s + 4 * l64);
        float c = w2q.x * hq.x + w2q.y * hq.y + w2q.z * hq.z + w2q.w * hq.w;
        c += __shfl_xor(c, 1);  c += __shfl_xor(c, 2);  c += __shfl_xor(c, 4);
        c += __shfl_xor(c, 8);  c += __shfl_xor(c, 16); c += __shfl_xor(c, 32);
        const bool par = ((c + b20) > 0.f) && (sp <= 63);

        if (par) {
            // mv2: push = Wcomb @ hmid + bcomb (parents only)
            const float* hp = hmid_s + hk * 128;
            float s = 0.f;
#pragma unroll
            for (int j = 0; j < 32; j++) {
                const float4 v = *(const float4*)(hp + 4 * j);
                s += wcr[j].x * v.x + wcr[j].y * v.y + wcr[j].z * v.z + wcr[j].w * v.w;
            }
            s += __shfl_xor(s, 1);
            if (hk == 0)                           // ll -> idx, rl -> idx+1
                stack_s[(idx + (o >> 7)) * 128 + (o & 127)] = s + bco;
            if (op < 64) pm0 |= (1ULL << op); else pm1 |= (1ULL << (op - 64));
            sp += 1;
        } else {
            sp -= 1;
        }
        op++;
        __syncthreads();                         // b2: stack update visible
    }

    if (t < 128) {
        int f = -1;
        if (t < op) f = (t < 64) ? (int)((pm0 >> t) & 1) : (int)((pm1 >> (t - 64)) & 1);
        rowflag[t] = f;
    }
}

// ---------------- Co1 = Hrec @ W2[1:].T + b2[1:] (scalar-path Hrec reads) ----------------
__global__ void co1_kernel(const float* __restrict__ Hrec, const float* __restrict__ W2,
                           const float* __restrict__ b2, float* __restrict__ Co1) {
    const int r = blockIdx.x;              // 0..127 (uniform -> scalar loads)
    const int c = threadIdx.x;             // 0..255
    const float* hr = Hrec + (size_t)r * HID;
    const float4* w = (const float4*)(W2 + (size_t)(1 + c) * HID);
    float acc = b2[1 + c];
#pragma unroll 8
    for (int k = 0; k < 64; k++) {
        const float4 a = w[k];
        const float4 hv = *(const float4*)(hr + 4 * k);
        acc += a.x * hv.x + a.y * hv.y + a.z * hv.z + a.w * hv.w;
    }
    Co1[(size_t)r * HID + c] = acc;
}

// ---------------- batched vocab matvecs; compacting + zeroing folded in ----------------
// Co1 rows read via wave-uniform scalar path (readfirstlane -> s_load broadcast).
__global__ __launch_bounds__(256, 1)
void value_kernel(const float* __restrict__ Co1, const int* __restrict__ rowflag,
                  const float* __restrict__ Wl, const float* __restrict__ bl,
                  const float* __restrict__ Wp, const float* __restrict__ bp,
                  float* __restrict__ out) {
    const int m = blockIdx.y;              // 0 = leaf (Wl) + zero rows, 1 = parent (Wp)
    const int t = threadIdx.x;
    const int v = blockIdx.x * 256 + t;    // 125 blocks x 256 = 32000
    __shared__ int list_s[128];
    __shared__ int zlist_s[128];
    __shared__ int nn_s, nz_s;
    if (t == 0) {
        int n = 0, znum = 0;
        for (int r = 0; r < 128; r++) {
            const int f = rowflag[r];
            if (f == m) list_s[n++] = r;
            else if (m == 0 && f == -1) zlist_s[znum++] = r;
        }
        nn_s = n; nz_s = znum;
    }
    __syncthreads();
    const int n = nn_s;
    const float* Wx = m ? Wp : Wl;
    const float* bx = m ? bp : bl;
    const float bv = bx[v];
    const float4* w4 = (const float4*)(Wx + (size_t)v * HID);

    for (int rc = 0; rc < n; rc += 32) {
        const int nr = min(32, n - rc);
        float acc[32];
#pragma unroll
        for (int rr = 0; rr < 32; rr++) acc[rr] = 0.f;
        for (int kc = 0; kc < 4; kc++) {
            float4 w[16];
#pragma unroll
            for (int i = 0; i < 16; i++) w[i] = w4[kc * 16 + i];
            for (int rr = 0; rr < nr; rr++) {
                const int row = __builtin_amdgcn_readfirstlane(list_s[rc + rr]);
                const float* cp = Co1 + (size_t)row * HID + kc * 64;
                float s = 0.f;
#pragma unroll
                for (int i = 0; i < 16; i++) {
                    const float4 c4 = *(const float4*)(cp + 4 * i);
                    s += w[i].x * c4.x + w[i].y * c4.y + w[i].z * c4.z + w[i].w * c4.w;
                }
                acc[rr] += s;
            }
        }
        for (int rr = 0; rr < nr; rr++) {
            const int row = __builtin_amdgcn_readfirstlane(list_s[rc + rr]);
            out[(size_t)row * VOC + v] = acc[rr] + bv;
        }
    }
    if (m == 0) {
        const int nz = nz_s;
        for (int i = 0; i < nz; i++) {
            const int row = __builtin_amdgcn_readfirstlane(zlist_s[i]);
            out[(size_t)row * VOC + v] = 0.f;
        }
    }
}

extern "C" void kernel_launch(void* const* d_in, const int* in_sizes, int n_in,
                              void* d_out, int out_size, void* d_ws, size_t ws_size,
                              hipStream_t stream) {
    const float* embed = (const float*)d_in[0];
    const float* Wpar  = (const float*)d_in[1];
    const float* bpar  = (const float*)d_in[2];
    const float* Wmu   = (const float*)d_in[3];
    const float* bmu   = (const float*)d_in[4];
    const float* Wlv   = (const float*)d_in[5];
    const float* blv   = (const float*)d_in[6];
    const float* W1    = (const float*)d_in[7];
    const float* b1    = (const float*)d_in[8];
    const float* W2    = (const float*)d_in[9];
    const float* b2    = (const float*)d_in[10];
    const float* Wl    = (const float*)d_in[11];
    const float* bl    = (const float*)d_in[12];
    const float* Wp    = (const float*)d_in[13];
    const float* bp    = (const float*)d_in[14];
    const float* eps   = (const float*)d_in[15];
    const int*  values = (const int*)d_in[16];

    float* ws = (float*)d_ws;
    float* h      = ws;                    // nodes 0..254 (65280 floats)
    float* z      = ws + 65280;            // 128
    float* Wcomb  = ws + 65408;            // 65536
    float* bcomb  = ws + 130944;           // 256
    float* Hrec   = ws + 131200;           // 128*256 = 32768
    float* Co1    = ws + 163968;           // 32768
    int*   rowflag = (int*)(ws + 196736);  // 128
    float* out = (float*)d_out;

    // collapsed push-weights (independent of encoder chain)
    wcomb_kernel<<<256, 256, 0, stream>>>(Wp, W2, b2, bp, Wcomb, bcomb);

    // encoder: levels (7,6) -> (5,4) -> (3..0 + root head)
    enc_level2<<<64, 256, 0, stream>>>(embed, values, Wpar, bpar, h, 63, 1);
    enc_level2<<<16, 256, 0, stream>>>(embed, values, Wpar, bpar, h, 15, 0);
    enc_tail<<<1, 256, 0, stream>>>(embed, values, Wpar, bpar, h,
                                    Wmu, bmu, Wlv, blv, eps, out, z);

    recur_kernel<<<1, 512, 0, stream>>>(W1, b1, W2, b2, Wcomb, bcomb, z, Hrec, rowflag);

    co1_kernel<<<128, 256, 0, stream>>>(Hrec, W2, b2, Co1);
    value_kernel<<<dim3(125, 2), 256, 0, stream>>>(Co1, rowflag, Wl, bl, Wp, bp, out);
}

// Round 5
// 389.794 us; speedup vs baseline: 2.1286x; 1.7406x over previous
//
#include <hip/hip_runtime.h>

#define HID 256
#define LAT 128
#define VOC 32000
#define NSTEP 128

// ---------------- coalesced per-level encoder ----------------
// One launch per tree level. Lane l keeps the three cat segments
// cat[4l+0..3], cat[256+4l..], cat[512+4l..] as registers (loaded via fully
// coalesced wave loads; identical addresses across waves -> L1 hits). Each
// output row r is one coalesced 1KB weight wave-load + 12 FMA + 6-shuffle
// reduce. Output rows split across (1<<rbshift) blocks per node.
__global__ __launch_bounds__(256)
void enc_nodes(const float* __restrict__ embed, const int* __restrict__ values,
               const float* __restrict__ Wpar, const float* __restrict__ bpar,
               float* __restrict__ h, int base, int rbshift) {
    const int rb   = blockIdx.x & ((1 << rbshift) - 1);
    const int node = base + (blockIdx.x >> rbshift);
    const int rowsPer = HID >> rbshift;
    const int t = threadIdx.x;
    const int w = t >> 6, l = t & 63;
    const int c1 = 2 * node + 1, c2 = 2 * node + 2;
    const float4 v0 = *(const float4*)(embed + (size_t)values[node] * HID + 4 * l);
    const float4 vA = (c1 >= 255)
        ? *(const float4*)(embed + (size_t)values[c1] * HID + 4 * l)
        : *(const float4*)(h + (size_t)c1 * HID + 4 * l);
    const float4 vB = (c2 >= 255)
        ? *(const float4*)(embed + (size_t)values[c2] * HID + 4 * l)
        : *(const float4*)(h + (size_t)c2 * HID + 4 * l);
    const int rpw = rowsPer >> 2;                  // rows per wave
    const int rbase = rb * rowsPer + w * rpw;
#pragma unroll 4
    for (int j = 0; j < rpw; j++) {
        const int r = rbase + j;
        const float* wr = Wpar + (size_t)r * 768;
        const float4 w0 = *(const float4*)(wr + 4 * l);
        const float4 w1 = *(const float4*)(wr + 256 + 4 * l);
        const float4 w2 = *(const float4*)(wr + 512 + 4 * l);
        float p = w0.x * v0.x + w0.y * v0.y + w0.z * v0.z + w0.w * v0.w;
        p += w1.x * vA.x + w1.y * vA.y + w1.z * vA.z + w1.w * vA.w;
        p += w2.x * vB.x + w2.y * vB.y + w2.z * vB.z + w2.w * vB.w;
        p += __shfl_xor(p, 1);  p += __shfl_xor(p, 2);  p += __shfl_xor(p, 4);
        p += __shfl_xor(p, 8);  p += __shfl_xor(p, 16); p += __shfl_xor(p, 32);
        if (l == 0) h[(size_t)node * HID + r] = p + bpar[r];
    }
}

// ---------------- root head: mu, logvar, z (coalesced) ----------------
__global__ __launch_bounds__(256)
void root_head(const float* __restrict__ h,
               const float* __restrict__ Wmu, const float* __restrict__ bmu,
               const float* __restrict__ Wlv, const float* __restrict__ blv,
               const float* __restrict__ eps,
               float* __restrict__ out, float* __restrict__ z) {
    const int t = threadIdx.x;
    const int w = t >> 6, l = t & 63;
    __shared__ float mu_s[128], lv_s[128];
    const float4 hv = *(const float4*)(h + 4 * l);    // root vector segment
#pragma unroll 4
    for (int j = 0; j < 64; j++) {
        const int vr = w * 64 + j;                    // 0..255: 0-127 mu, 128-255 lv
        const int r = vr & 127;
        const float* Wrow = (vr < 128 ? Wmu : Wlv) + (size_t)r * HID;
        const float4 a = *(const float4*)(Wrow + 4 * l);
        float p = a.x * hv.x + a.y * hv.y + a.z * hv.z + a.w * hv.w;
        p += __shfl_xor(p, 1);  p += __shfl_xor(p, 2);  p += __shfl_xor(p, 4);
        p += __shfl_xor(p, 8);  p += __shfl_xor(p, 16); p += __shfl_xor(p, 32);
        if (l == 0) {
            if (vr < 128) mu_s[r] = p + bmu[r];
            else          lv_s[r] = p + blv[r];
        }
    }
    __syncthreads();
    if (t < 128) {
        const float m = mu_s[t], lv = lv_s[t];
        out[(size_t)NSTEP * VOC + t] = m;
        out[(size_t)NSTEP * VOC + 128 + t] = lv;
        z[t] = m + eps[t] * expf(0.5f * lv);
    }
}

// ---------------- precompute Wcomb = Wp_tail @ W2[1:], bcomb ----------------
__global__ void wcomb_kernel(const float* __restrict__ Wp, const float* __restrict__ W2,
                             const float* __restrict__ b2, const float* __restrict__ bp,
                             float* __restrict__ Wcomb, float* __restrict__ bcomb) {
    const int o = blockIdx.x;              // 0..255
    const int k = threadIdx.x;             // 0..255
    __shared__ float wpt_s[256];
    __shared__ float red_s[4];
    wpt_s[k] = Wp[(size_t)(VOC + o) * HID + k];
    __syncthreads();
    float acc = 0.f;
#pragma unroll 8
    for (int j = 0; j < 256; j++)
        acc += wpt_s[j] * W2[(size_t)(1 + j) * HID + k];
    Wcomb[(size_t)o * HID + k] = acc;
    float p = wpt_s[k] * b2[1 + k];
    p += __shfl_xor(p, 1);  p += __shfl_xor(p, 2);  p += __shfl_xor(p, 4);
    p += __shfl_xor(p, 8);  p += __shfl_xor(p, 16); p += __shfl_xor(p, 32);
    if ((k & 63) == 0) red_s[k >> 6] = p;
    __syncthreads();
    if (k == 0) bcomb[o] = bp[VOC + o] + red_s[0] + red_s[1] + red_s[2] + red_s[3];
}

// ---------------- sequential decoder recurrence (unchanged from R4) ----------------
__global__ __launch_bounds__(512, 2)
void recur_kernel(const float* W1, const float* b1,
                  const float* W2, const float* b2,
                  const float* Wcomb, const float* bcomb,
                  const float* z,
                  float* Hrec, int* rowflag) {
    const int t = threadIdx.x;
    const int o = t >> 1;                  // 0..255
    const int hk = t & 1;
    __shared__ __align__(16) float stack_s[64 * 128];   // 32 KB
    __shared__ __align__(16) float hmid_s[256];

    // resident weights (pointers not __restrict + global store in loop ->
    // compiler cannot rematerialize; weights stay in VGPRs)
    float4 w1r[16];
#pragma unroll
    for (int j = 0; j < 16; j++)
        w1r[j] = *(const float4*)(W1 + (size_t)o * 128 + hk * 64 + 4 * j);
    float4 wcr[32];
#pragma unroll
    for (int j = 0; j < 32; j++)
        wcr[j] = *(const float4*)(Wcomb + (size_t)o * 256 + hk * 128 + 4 * j);

    const float b1o = b1[o];
    const float bco = bcomb[o];
    const float b20 = b2[0];
    const int l64 = t & 63;
    const float4 w2q = *(const float4*)(W2 + 4 * l64);

    if (t < 128) stack_s[t] = z[t];
    int sp = 1, op = 0;
    unsigned long long pm0 = 0ULL, pm1 = 0ULL;
    __syncthreads();

    for (int step = 0; step < NSTEP; step++) {
        if (sp <= 0) break;
        const int idx = sp - 1;

        // mv1: hmid = lrelu(W1 @ node + b1), split-K=2 (even/odd lanes)
        const float* np = stack_s + idx * 128 + hk * 64;
        float a = 0.f;
#pragma unroll
        for (int j = 0; j < 16; j++) {
            const float4 v = *(const float4*)(np + 4 * j);
            a += w1r[j].x * v.x + w1r[j].y * v.y + w1r[j].z * v.z + w1r[j].w * v.w;
        }
        a += __shfl_xor(a, 1);
        if (hk == 0) {
            float pre = a + b1o;
            pre = pre > 0.f ? pre : 0.2f * pre;
            hmid_s[o] = pre;
            Hrec[(size_t)op * HID + o] = pre;   // remat-blocker + record
        }
        __syncthreads();                         // b1: hmid visible

        // c0 decision dot: every wave redundantly (identical result)
        const float4 hq = *(const float4*)(hmid_s + 4 * l64);
        float c = w2q.x * hq.x + w2q.y * hq.y + w2q.z * hq.z + w2q.w * hq.w;
        c += __shfl_xor(c, 1);  c += __shfl_xor(c, 2);  c += __shfl_xor(c, 4);
        c += __shfl_xor(c, 8);  c += __shfl_xor(c, 16); c += __shfl_xor(c, 32);
        const bool par = ((c + b20) > 0.f) && (sp <= 63);

        if (par) {
            // mv2: push = Wcomb @ hmid + bcomb (parents only)
            const float* hp = hmid_s + hk * 128;
            float s = 0.f;
#pragma unroll
            for (int j = 0; j < 32; j++) {
                const float4 v = *(const float4*)(hp + 4 * j);
                s += wcr[j].x * v.x + wcr[j].y * v.y + wcr[j].z * v.z + wcr[j].w * v.w;
            }
            s += __shfl_xor(s, 1);
            if (hk == 0)                           // ll -> idx, rl -> idx+1
                stack_s[(idx + (o >> 7)) * 128 + (o & 127)] = s + bco;
            if (op < 64) pm0 |= (1ULL << op); else pm1 |= (1ULL << (op - 64));
            sp += 1;
        } else {
            sp -= 1;
        }
        op++;
        __syncthreads();                         // b2: stack update visible
    }

    if (t < 128) {
        int f = -1;
        if (t < op) f = (t < 64) ? (int)((pm0 >> t) & 1) : (int)((pm1 >> (t - 64)) & 1);
        rowflag[t] = f;
    }
}

// ---------------- Co1 = Hrec @ W2[1:].T + b2[1:] (scalar-path Hrec reads) ----------------
__global__ void co1_kernel(const float* __restrict__ Hrec, const float* __restrict__ W2,
                           const float* __restrict__ b2, float* __restrict__ Co1) {
    const int r = blockIdx.x;              // 0..127 (uniform -> scalar loads)
    const int c = threadIdx.x;             // 0..255
    const float* hr = Hrec + (size_t)r * HID;
    const float4* w = (const float4*)(W2 + (size_t)(1 + c) * HID);
    float acc = b2[1 + c];
#pragma unroll 8
    for (int k = 0; k < 64; k++) {
        const float4 a = w[k];
        const float4 hv = *(const float4*)(hr + 4 * k);
        acc += a.x * hv.x + a.y * hv.y + a.z * hv.z + a.w * hv.w;
    }
    Co1[(size_t)r * HID + c] = acc;
}

// ---------------- batched vocab matvecs; compacting + zeroing folded in ----------------
__global__ __launch_bounds__(256, 1)
void value_kernel(const float* __restrict__ Co1, const int* __restrict__ rowflag,
                  const float* __restrict__ Wl, const float* __restrict__ bl,
                  const float* __restrict__ Wp, const float* __restrict__ bp,
                  float* __restrict__ out) {
    const int m = blockIdx.y;              // 0 = leaf (Wl) + zero rows, 1 = parent (Wp)
    const int t = threadIdx.x;
    const int v = blockIdx.x * 256 + t;    // 125 blocks x 256 = 32000
    __shared__ int list_s[128];
    __shared__ int zlist_s[128];
    __shared__ int nn_s, nz_s;
    if (t == 0) {
        int n = 0, znum = 0;
        for (int r = 0; r < 128; r++) {
            const int f = rowflag[r];
            if (f == m) list_s[n++] = r;
            else if (m == 0 && f == -1) zlist_s[znum++] = r;
        }
        nn_s = n; nz_s = znum;
    }
    __syncthreads();
    const int n = nn_s;
    const float* Wx = m ? Wp : Wl;
    const float* bx = m ? bp : bl;
    const float bv = bx[v];
    const float4* w4 = (const float4*)(Wx + (size_t)v * HID);

    for (int rc = 0; rc < n; rc += 32) {
        const int nr = min(32, n - rc);
        float acc[32];
#pragma unroll
        for (int rr = 0; rr < 32; rr++) acc[rr] = 0.f;
        for (int kc = 0; kc < 4; kc++) {
            float4 w[16];
#pragma unroll
            for (int i = 0; i < 16; i++) w[i] = w4[kc * 16 + i];
            for (int rr = 0; rr < nr; rr++) {
                const int row = __builtin_amdgcn_readfirstlane(list_s[rc + rr]);
                const float* cp = Co1 + (size_t)row * HID + kc * 64;
                float s = 0.f;
#pragma unroll
                for (int i = 0; i < 16; i++) {
                    const float4 c4 = *(const float4*)(cp + 4 * i);
                    s += w[i].x * c4.x + w[i].y * c4.y + w[i].z * c4.z + w[i].w * c4.w;
                }
                acc[rr] += s;
            }
        }
        for (int rr = 0; rr < nr; rr++) {
            const int row = __builtin_amdgcn_readfirstlane(list_s[rc + rr]);
            out[(size_t)row * VOC + v] = acc[rr] + bv;
        }
    }
    if (m == 0) {
        const int nz = nz_s;
        for (int i = 0; i < nz; i++) {
            const int row = __builtin_amdgcn_readfirstlane(zlist_s[i]);
            out[(size_t)row * VOC + v] = 0.f;
        }
    }
}

extern "C" void kernel_launch(void* const* d_in, const int* in_sizes, int n_in,
                              void* d_out, int out_size, void* d_ws, size_t ws_size,
                              hipStream_t stream) {
    const float* embed = (const float*)d_in[0];
    const float* Wpar  = (const float*)d_in[1];
    const float* bpar  = (const float*)d_in[2];
    const float* Wmu   = (const float*)d_in[3];
    const float* bmu   = (const float*)d_in[4];
    const float* Wlv   = (const float*)d_in[5];
    const float* blv   = (const float*)d_in[6];
    const float* W1    = (const float*)d_in[7];
    const float* b1    = (const float*)d_in[8];
    const float* W2    = (const float*)d_in[9];
    const float* b2    = (const float*)d_in[10];
    const float* Wl    = (const float*)d_in[11];
    const float* bl    = (const float*)d_in[12];
    const float* Wp    = (const float*)d_in[13];
    const float* bp    = (const float*)d_in[14];
    const float* eps   = (const float*)d_in[15];
    const int*  values = (const int*)d_in[16];

    float* ws = (float*)d_ws;
    float* h      = ws;                    // nodes 0..254 (65280 floats)
    float* z      = ws + 65280;            // 128
    float* Wcomb  = ws + 65408;            // 65536
    float* bcomb  = ws + 130944;           // 256
    float* Hrec   = ws + 131200;           // 128*256 = 32768
    float* Co1    = ws + 163968;           // 32768
    int*   rowflag = (int*)(ws + 196736);  // 128
    float* out = (float*)d_out;

    // collapsed push-weights (independent of encoder chain)
    wcomb_kernel<<<256, 256, 0, stream>>>(Wp, W2, b2, bp, Wcomb, bcomb);

    // encoder: one coalesced launch per level (nodes x rowblocks)
    enc_nodes<<<128, 256, 0, stream>>>(embed, values, Wpar, bpar, h, 127, 0); // L7
    enc_nodes<<< 64, 256, 0, stream>>>(embed, values, Wpar, bpar, h,  63, 0); // L6
    enc_nodes<<< 64, 256, 0, stream>>>(embed, values, Wpar, bpar, h,  31, 1); // L5
    enc_nodes<<< 64, 256, 0, stream>>>(embed, values, Wpar, bpar, h,  15, 2); // L4
    enc_nodes<<< 64, 256, 0, stream>>>(embed, values, Wpar, bpar, h,   7, 3); // L3
    enc_nodes<<< 64, 256, 0, stream>>>(embed, values, Wpar, bpar, h,   3, 4); // L2
    enc_nodes<<< 32, 256, 0, stream>>>(embed, values, Wpar, bpar, h,   1, 4); // L1
    enc_nodes<<< 16, 256, 0, stream>>>(embed, values, Wpar, bpar, h,   0, 4); // L0

    root_head<<<1, 256, 0, stream>>>(h, Wmu, bmu, Wlv, blv, eps, out, z);

    recur_kernel<<<1, 512, 0, stream>>>(W1, b1, W2, b2, Wcomb, bcomb, z, Hrec, rowflag);

    co1_kernel<<<128, 256, 0, stream>>>(Hrec, W2, b2, Co1);
    value_kernel<<<dim3(125, 2), 256, 0, stream>>>(Co1, rowflag, Wl, bl, Wp, bp, out);
}

// Round 6
// 296.983 us; speedup vs baseline: 2.7938x; 1.3125x over previous
//
#include <hip/hip_runtime.h>

#define HID 256
#define LAT 128
#define VOC 32000
#define NSTEP 128

// ---------------- prep: wcomb + block-transposed weight packs ----------------
// Wq layouts: Wq[k4*R + r] (float4) = W[r][4k4..4k4+3]  -> thread-per-row
// matvecs get lane-consecutive (coalesced) weight loads.
__global__ __launch_bounds__(256)
void prep_kernel(const float* __restrict__ Wp, const float* __restrict__ W2,
                 const float* __restrict__ b2, const float* __restrict__ bp,
                 const float* __restrict__ Wpar,
                 const float* __restrict__ Wmu, const float* __restrict__ Wlv,
                 float* __restrict__ Wcomb, float* __restrict__ bcomb,
                 float* __restrict__ Wq_par, float* __restrict__ Wq_mu,
                 float* __restrict__ Wq_lv, float* __restrict__ Wq_w2) {
    const int b = blockIdx.x;
    const int t = threadIdx.x;
    if (b < 256) {                     // Wcomb = Wp_tail @ W2[1:], bcomb
        const int o = b, k = t;
        __shared__ float wpt_s[256];
        __shared__ float red_s[4];
        wpt_s[k] = Wp[(size_t)(VOC + o) * HID + k];
        __syncthreads();
        float acc = 0.f;
#pragma unroll 8
        for (int j = 0; j < 256; j++)
            acc += wpt_s[j] * W2[(size_t)(1 + j) * HID + k];
        Wcomb[(size_t)o * HID + k] = acc;
        float p = wpt_s[k] * b2[1 + k];
        p += __shfl_xor(p, 1);  p += __shfl_xor(p, 2);  p += __shfl_xor(p, 4);
        p += __shfl_xor(p, 8);  p += __shfl_xor(p, 16); p += __shfl_xor(p, 32);
        if ((k & 63) == 0) red_s[k >> 6] = p;
        __syncthreads();
        if (k == 0) bcomb[o] = bp[VOC + o] + red_s[0] + red_s[1] + red_s[2] + red_s[3];
    } else if (b < 448) {              // Wpar pack: 192 k4-rows x 256
        const int k4 = b - 256;
        const float4 v = *(const float4*)(Wpar + (size_t)t * 768 + 4 * k4);
        ((float4*)Wq_par)[k4 * 256 + t] = v;
    } else if (b < 512) {              // Wmu / Wlv pack: 64 k4-rows x 128 each
        const int k4 = b - 448;
        const int r = t & 127;
        const float* src = (t < 128 ? Wmu : Wlv) + (size_t)r * HID + 4 * k4;
        const float4 v = *(const float4*)src;
        ((float4*)(t < 128 ? Wq_mu : Wq_lv))[k4 * 128 + r] = v;
    } else {                           // W2[1:] pack: 64 k4-rows x 256
        const int k4 = b - 512;
        const float4 v = *(const float4*)(W2 + (size_t)(1 + t) * HID + 4 * k4);
        ((float4*)Wq_w2)[k4 * 256 + t] = v;
    }
}

// ---------------- fused two-level encoder (thread-per-row, packed weights) ----
// Block handles parent i = base+blockIdx.x: computes its two children (kept in
// LDS + stored to h), then itself. Weight loads coalesced; cat reads broadcast.
__global__ __launch_bounds__(256)
void enc2(const float* __restrict__ embed, const int* __restrict__ values,
          const float* __restrict__ Wq, const float* __restrict__ bpar,
          float* __restrict__ h, int base) {
    const int i = base + blockIdx.x;
    const int t = threadIdx.x;
    __shared__ __align__(16) float cat[768];
    __shared__ float hc[2][256];
    const float bv = bpar[t];
    const float4* wq = (const float4*)Wq + t;

    for (int s = 0; s < 2; s++) {
        const int c = 2 * i + 1 + s;
        cat[t] = embed[(size_t)values[c] * HID + t];
        const int g1 = 2 * c + 1, g2 = 2 * c + 2;
        cat[256 + t] = (g1 >= 255) ? embed[(size_t)values[g1] * HID + t]
                                   : h[(size_t)g1 * HID + t];
        cat[512 + t] = (g2 >= 255) ? embed[(size_t)values[g2] * HID + t]
                                   : h[(size_t)g2 * HID + t];
        __syncthreads();
        float acc = bv;
        const float4* c4 = (const float4*)cat;
#pragma unroll 8
        for (int k4 = 0; k4 < 192; k4++) {
            const float4 w = wq[k4 * 256];
            const float4 cc = c4[k4];
            acc += w.x * cc.x + w.y * cc.y + w.z * cc.z + w.w * cc.w;
        }
        hc[s][t] = acc;
        h[(size_t)c * HID + t] = acc;
        __syncthreads();
    }
    cat[t] = embed[(size_t)values[i] * HID + t];
    cat[256 + t] = hc[0][t];
    cat[512 + t] = hc[1][t];
    __syncthreads();
    float acc = bv;
    const float4* c4 = (const float4*)cat;
#pragma unroll 8
    for (int k4 = 0; k4 < 192; k4++) {
        const float4 w = wq[k4 * 256];
        const float4 cc = c4[k4];
        acc += w.x * cc.x + w.y * cc.y + w.z * cc.z + w.w * cc.w;
    }
    h[(size_t)i * HID + t] = acc;
}

// ---------------- final block: nodes 1,2,0 + root head + z ----------------
__global__ __launch_bounds__(256)
void enc_final(const float* __restrict__ embed, const int* __restrict__ values,
               const float* __restrict__ Wq, const float* __restrict__ bpar,
               const float* __restrict__ h,
               const float* __restrict__ Wq_mu, const float* __restrict__ bmu,
               const float* __restrict__ Wq_lv, const float* __restrict__ blv,
               const float* __restrict__ eps,
               float* __restrict__ out, float* __restrict__ z) {
    const int t = threadIdx.x;
    __shared__ __align__(16) float cat[768];
    __shared__ float hc[2][256];
    __shared__ __align__(16) float r0[256];
    __shared__ float mu_s[128], lv_s[128];
    const float bv = bpar[t];
    const float4* wq = (const float4*)Wq + t;

    for (int s = 0; s < 2; s++) {
        const int c = 1 + s;                       // nodes 1,2; children 3,4 / 5,6
        cat[t] = embed[(size_t)values[c] * HID + t];
        cat[256 + t] = h[(size_t)(2 * c + 1) * HID + t];
        cat[512 + t] = h[(size_t)(2 * c + 2) * HID + t];
        __syncthreads();
        float acc = bv;
        const float4* c4 = (const float4*)cat;
#pragma unroll 8
        for (int k4 = 0; k4 < 192; k4++) {
            const float4 w = wq[k4 * 256];
            const float4 cc = c4[k4];
            acc += w.x * cc.x + w.y * cc.y + w.z * cc.z + w.w * cc.w;
        }
        hc[s][t] = acc;
        __syncthreads();
    }
    cat[t] = embed[(size_t)values[0] * HID + t];
    cat[256 + t] = hc[0][t];
    cat[512 + t] = hc[1][t];
    __syncthreads();
    {
        float acc = bv;
        const float4* c4 = (const float4*)cat;
#pragma unroll 8
        for (int k4 = 0; k4 < 192; k4++) {
            const float4 w = wq[k4 * 256];
            const float4 cc = c4[k4];
            acc += w.x * cc.x + w.y * cc.y + w.z * cc.z + w.w * cc.w;
        }
        r0[t] = acc;
    }
    __syncthreads();
    // root head: threads 0-127 mu rows, 128-255 lv rows (packed, coalesced)
    const int r = t & 127;
    const float4* wqh = (const float4*)(t < 128 ? Wq_mu : Wq_lv) + r;
    float acc2 = (t < 128) ? bmu[r] : blv[r];
    const float4* r4 = (const float4*)r0;
#pragma unroll 8
    for (int k4 = 0; k4 < 64; k4++) {
        const float4 w = wqh[k4 * 128];
        const float4 cc = r4[k4];
        acc2 += w.x * cc.x + w.y * cc.y + w.z * cc.z + w.w * cc.w;
    }
    if (t < 128) { out[(size_t)NSTEP * VOC + r] = acc2;       mu_s[r] = acc2; }
    else         { out[(size_t)NSTEP * VOC + 128 + r] = acc2; lv_s[r] = acc2; }
    __syncthreads();
    if (t < 128) z[t] = mu_s[t] + eps[t] * expf(0.5f * lv_s[t]);
}

// ---------------- sequential decoder recurrence (unchanged, known-good) ------
__global__ __launch_bounds__(512, 2)
void recur_kernel(const float* W1, const float* b1,
                  const float* W2, const float* b2,
                  const float* Wcomb, const float* bcomb,
                  const float* z,
                  float* Hrec, int* rowflag) {
    const int t = threadIdx.x;
    const int o = t >> 1;                  // 0..255
    const int hk = t & 1;
    __shared__ __align__(16) float stack_s[64 * 128];   // 32 KB
    __shared__ __align__(16) float hmid_s[256];

    // resident weights (pointers not __restrict + global store in loop ->
    // compiler cannot rematerialize; weights stay in VGPRs)
    float4 w1r[16];
#pragma unroll
    for (int j = 0; j < 16; j++)
        w1r[j] = *(const float4*)(W1 + (size_t)o * 128 + hk * 64 + 4 * j);
    float4 wcr[32];
#pragma unroll
    for (int j = 0; j < 32; j++)
        wcr[j] = *(const float4*)(Wcomb + (size_t)o * 256 + hk * 128 + 4 * j);

    const float b1o = b1[o];
    const float bco = bcomb[o];
    const float b20 = b2[0];
    const int l64 = t & 63;
    const float4 w2q = *(const float4*)(W2 + 4 * l64);

    if (t < 128) stack_s[t] = z[t];
    int sp = 1, op = 0;
    unsigned long long pm0 = 0ULL, pm1 = 0ULL;
    __syncthreads();

    for (int step = 0; step < NSTEP; step++) {
        if (sp <= 0) break;
        const int idx = sp - 1;

        // mv1: hmid = lrelu(W1 @ node + b1), split-K=2 (even/odd lanes)
        const float* np = stack_s + idx * 128 + hk * 64;
        float a = 0.f;
#pragma unroll
        for (int j = 0; j < 16; j++) {
            const float4 v = *(const float4*)(np + 4 * j);
            a += w1r[j].x * v.x + w1r[j].y * v.y + w1r[j].z * v.z + w1r[j].w * v.w;
        }
        a += __shfl_xor(a, 1);
        if (hk == 0) {
            float pre = a + b1o;
            pre = pre > 0.f ? pre : 0.2f * pre;
            hmid_s[o] = pre;
            Hrec[(size_t)op * HID + o] = pre;   // remat-blocker + record
        }
        __syncthreads();                         // b1: hmid visible

        // c0 decision dot: every wave redundantly (identical result)
        const float4 hq = *(const float4*)(hmid_s + 4 * l64);
        float c = w2q.x * hq.x + w2q.y * hq.y + w2q.z * hq.z + w2q.w * hq.w;
        c += __shfl_xor(c, 1);  c += __shfl_xor(c, 2);  c += __shfl_xor(c, 4);
        c += __shfl_xor(c, 8);  c += __shfl_xor(c, 16); c += __shfl_xor(c, 32);
        const bool par = ((c + b20) > 0.f) && (sp <= 63);

        if (par) {
            // mv2: push = Wcomb @ hmid + bcomb (parents only)
            const float* hp = hmid_s + hk * 128;
            float s = 0.f;
#pragma unroll
            for (int j = 0; j < 32; j++) {
                const float4 v = *(const float4*)(hp + 4 * j);
                s += wcr[j].x * v.x + wcr[j].y * v.y + wcr[j].z * v.z + wcr[j].w * v.w;
            }
            s += __shfl_xor(s, 1);
            if (hk == 0)                           // ll -> idx, rl -> idx+1
                stack_s[(idx + (o >> 7)) * 128 + (o & 127)] = s + bco;
            if (op < 64) pm0 |= (1ULL << op); else pm1 |= (1ULL << (op - 64));
            sp += 1;
        } else {
            sp -= 1;
        }
        op++;
        __syncthreads();                         // b2: stack update visible
    }

    if (t < 128) {
        int f = -1;
        if (t < op) f = (t < 64) ? (int)((pm0 >> t) & 1) : (int)((pm1 >> (t - 64)) & 1);
        rowflag[t] = f;
    }
}

// ---------------- Co1 = Hrec @ W2[1:].T + b2[1:] (packed, coalesced) ---------
__global__ __launch_bounds__(256)
void co1_kernel(const float* __restrict__ Hrec, const float* __restrict__ Wq_w2,
                const float* __restrict__ b2, float* __restrict__ Co1) {
    const int r = blockIdx.x;              // 0..127
    const int c = threadIdx.x;             // 0..255
    __shared__ __align__(16) float hs[256];
    hs[c] = Hrec[(size_t)r * HID + c];
    __syncthreads();
    float acc = b2[1 + c];
    const float4* wq = (const float4*)Wq_w2 + c;
    const float4* h4 = (const float4*)hs;
#pragma unroll 8
    for (int k4 = 0; k4 < 64; k4++) {
        const float4 a = wq[k4 * 256];
        const float4 hv = h4[k4];
        acc += a.x * hv.x + a.y * hv.y + a.z * hv.z + a.w * hv.w;
    }
    Co1[(size_t)r * HID + c] = acc;
}

// ---------------- batched vocab matvecs (unchanged, known-good) --------------
__global__ __launch_bounds__(256, 1)
void value_kernel(const float* __restrict__ Co1, const int* __restrict__ rowflag,
                  const float* __restrict__ Wl, const float* __restrict__ bl,
                  const float* __restrict__ Wp, const float* __restrict__ bp,
                  float* __restrict__ out) {
    const int m = blockIdx.y;              // 0 = leaf (Wl) + zero rows, 1 = parent (Wp)
    const int t = threadIdx.x;
    const int v = blockIdx.x * 256 + t;    // 125 blocks x 256 = 32000
    __shared__ int list_s[128];
    __shared__ int zlist_s[128];
    __shared__ int nn_s, nz_s;
    if (t == 0) {
        int n = 0, znum = 0;
        for (int r = 0; r < 128; r++) {
            const int f = rowflag[r];
            if (f == m) list_s[n++] = r;
            else if (m == 0 && f == -1) zlist_s[znum++] = r;
        }
        nn_s = n; nz_s = znum;
    }
    __syncthreads();
    const int n = nn_s;
    const float* Wx = m ? Wp : Wl;
    const float* bx = m ? bp : bl;
    const float bv = bx[v];
    const float4* w4 = (const float4*)(Wx + (size_t)v * HID);

    for (int rc = 0; rc < n; rc += 32) {
        const int nr = min(32, n - rc);
        float acc[32];
#pragma unroll
        for (int rr = 0; rr < 32; rr++) acc[rr] = 0.f;
        for (int kc = 0; kc < 4; kc++) {
            float4 w[16];
#pragma unroll
            for (int i = 0; i < 16; i++) w[i] = w4[kc * 16 + i];
            for (int rr = 0; rr < nr; rr++) {
                const int row = __builtin_amdgcn_readfirstlane(list_s[rc + rr]);
                const float* cp = Co1 + (size_t)row * HID + kc * 64;
                float s = 0.f;
#pragma unroll
                for (int i = 0; i < 16; i++) {
                    const float4 c4 = *(const float4*)(cp + 4 * i);
                    s += w[i].x * c4.x + w[i].y * c4.y + w[i].z * c4.z + w[i].w * c4.w;
                }
                acc[rr] += s;
            }
        }
        for (int rr = 0; rr < nr; rr++) {
            const int row = __builtin_amdgcn_readfirstlane(list_s[rc + rr]);
            out[(size_t)row * VOC + v] = acc[rr] + bv;
        }
    }
    if (m == 0) {
        const int nz = nz_s;
        for (int i = 0; i < nz; i++) {
            const int row = __builtin_amdgcn_readfirstlane(zlist_s[i]);
            out[(size_t)row * VOC + v] = 0.f;
        }
    }
}

extern "C" void kernel_launch(void* const* d_in, const int* in_sizes, int n_in,
                              void* d_out, int out_size, void* d_ws, size_t ws_size,
                              hipStream_t stream) {
    const float* embed = (const float*)d_in[0];
    const float* Wpar  = (const float*)d_in[1];
    const float* bpar  = (const float*)d_in[2];
    const float* Wmu   = (const float*)d_in[3];
    const float* bmu   = (const float*)d_in[4];
    const float* Wlv   = (const float*)d_in[5];
    const float* blv   = (const float*)d_in[6];
    const float* W1    = (const float*)d_in[7];
    const float* b1    = (const float*)d_in[8];
    const float* W2    = (const float*)d_in[9];
    const float* b2    = (const float*)d_in[10];
    const float* Wl    = (const float*)d_in[11];
    const float* bl    = (const float*)d_in[12];
    const float* Wp    = (const float*)d_in[13];
    const float* bp    = (const float*)d_in[14];
    const float* eps   = (const float*)d_in[15];
    const int*  values = (const int*)d_in[16];

    float* ws = (float*)d_ws;
    float* h       = ws;                    // 255*256 = 65280
    float* z       = ws + 65280;            // 128
    float* Wcomb   = ws + 65408;            // 65536
    float* bcomb   = ws + 130944;           // 256
    float* Hrec    = ws + 131200;           // 32768
    float* Co1     = ws + 163968;           // 32768
    int*   rowflag = (int*)(ws + 196736);   // 128
    float* Wq_par  = ws + 196864;           // 196608
    float* Wq_mu   = ws + 393472;           // 32768
    float* Wq_lv   = ws + 426240;           // 32768
    float* Wq_w2   = ws + 459008;           // 65536  (end: 524544 floats ~= 2.1 MB)
    float* out = (float*)d_out;

    // prep: wcomb (256 blk) + Wpar pack (192) + Wmu/Wlv pack (64) + W2 pack (64)
    prep_kernel<<<576, 256, 0, stream>>>(Wp, W2, b2, bp, Wpar, Wmu, Wlv,
                                         Wcomb, bcomb, Wq_par, Wq_mu, Wq_lv, Wq_w2);

    // encoder: fused level pairs (6,7) -> (4,5) -> (2,3) -> (0,1)+head
    enc2<<<64, 256, 0, stream>>>(embed, values, Wq_par, bpar, h, 63);
    enc2<<<16, 256, 0, stream>>>(embed, values, Wq_par, bpar, h, 15);
    enc2<<< 4, 256, 0, stream>>>(embed, values, Wq_par, bpar, h,  3);
    enc_final<<<1, 256, 0, stream>>>(embed, values, Wq_par, bpar, h,
                                     Wq_mu, bmu, Wq_lv, blv, eps, out, z);

    recur_kernel<<<1, 512, 0, stream>>>(W1, b1, W2, b2, Wcomb, bcomb, z, Hrec, rowflag);

    co1_kernel<<<128, 256, 0, stream>>>(Hrec, Wq_w2, b2, Co1);
    value_kernel<<<dim3(125, 2), 256, 0, stream>>>(Co1, rowflag, Wl, bl, Wp, bp, out);
}

// Round 7
// 283.242 us; speedup vs baseline: 2.9293x; 1.0485x over previous
//
#include <hip/hip_runtime.h>

#define HID 256
#define LAT 128
#define VOC 32000
#define NSTEP 128

// ---------------- prep: wcomb (split-j) + block-transposed weight packs ------
// Wq layouts: Wq[k4*R + r] (float4) = W[r][4k4..4k4+3]  -> thread-per-row
// matvecs get lane-consecutive (coalesced) weight loads.
__global__ __launch_bounds__(512)
void prep_kernel(const float* __restrict__ Wp, const float* __restrict__ W2,
                 const float* __restrict__ b2, const float* __restrict__ bp,
                 const float* __restrict__ Wpar,
                 const float* __restrict__ Wmu, const float* __restrict__ Wlv,
                 float* __restrict__ Wcomb, float* __restrict__ bcomb,
                 float* __restrict__ Wq_par, float* __restrict__ Wq_mu,
                 float* __restrict__ Wq_lv, float* __restrict__ Wq_w2) {
    const int b = blockIdx.x;
    const int t = threadIdx.x;
    if (b < 256) {                     // Wcomb row o = Wp_tail[o] @ W2[1:], bcomb[o]
        const int o = b;
        const int k = t & 255, jh = t >> 8;
        __shared__ float wpt_s[256];
        __shared__ float part_s[2][256];
        __shared__ float red_s[4];
        if (t < 256) wpt_s[t] = Wp[(size_t)(VOC + o) * HID + t];
        __syncthreads();
        float acc = 0.f;
#pragma unroll 8
        for (int j = 0; j < 128; j++)
            acc += wpt_s[jh * 128 + j] * W2[(size_t)(1 + jh * 128 + j) * HID + k];
        part_s[jh][k] = acc;
        if (t < 256) {
            float p = wpt_s[k] * b2[1 + k];
            p += __shfl_xor(p, 1);  p += __shfl_xor(p, 2);  p += __shfl_xor(p, 4);
            p += __shfl_xor(p, 8);  p += __shfl_xor(p, 16); p += __shfl_xor(p, 32);
            if ((k & 63) == 0) red_s[k >> 6] = p;
        }
        __syncthreads();
        if (t < 256) Wcomb[(size_t)o * HID + k] = part_s[0][k] + part_s[1][k];
        if (t == 0) bcomb[o] = bp[VOC + o] + red_s[0] + red_s[1] + red_s[2] + red_s[3];
    } else if (b < 352) {              // Wpar pack: 96 blocks x 2 k4
        const int k4 = (b - 256) * 2 + (t >> 8);
        const int r = t & 255;
        ((float4*)Wq_par)[k4 * 256 + r] = *(const float4*)(Wpar + (size_t)r * 768 + 4 * k4);
    } else if (b < 384) {              // Wmu/Wlv pack: 32 blocks x 2 k4
        const int k4 = (b - 352) * 2 + (t >> 8);
        const int r = t & 127, sel = (t >> 7) & 1;
        const float* src = (sel ? Wlv : Wmu) + (size_t)r * HID + 4 * k4;
        ((float4*)(sel ? Wq_lv : Wq_mu))[k4 * 128 + r] = *(const float4*)src;
    } else {                           // W2[1:] pack: 32 blocks x 2 k4
        const int k4 = (b - 384) * 2 + (t >> 8);
        const int r = t & 255;
        ((float4*)Wq_w2)[k4 * 256 + r] = *(const float4*)(W2 + (size_t)(1 + r) * HID + 4 * k4);
    }
}

// ---------------- fused two-level encoder: children in PARALLEL --------------
// 1024 threads. Phase 1: both children simultaneously (256 threads x split-K=2
// each). Phase 2: parent with split-K=4. Only the parent h row is stored
// (middle-child rows are never read downstream).
__global__ __launch_bounds__(1024)
void enc2(const float* __restrict__ embed, const int* __restrict__ values,
          const float* __restrict__ Wq, const float* __restrict__ bpar,
          float* __restrict__ h, int base) {
    const int i = base + blockIdx.x;
    const int t = threadIdx.x;
    const int o = t & 255;
    const int g = t >> 8;              // 0..3
    const int cid = g & 1, kh = g >> 1;
    __shared__ __align__(16) float cat[2][768];
    __shared__ float part[4][256];
    __shared__ __align__(16) float pcat[768];

    // stage both children's cat vectors (1536 elements)
    const int c0n = 2 * i + 1;
    for (int q = t; q < 1536; q += 1024) {
        const int cc = (q >= 768);
        const int e = q - cc * 768;
        const int node = c0n + cc;
        const int seg = e >> 8, idx = e & 255;
        float v;
        if (seg == 0) v = embed[(size_t)values[node] * HID + idx];
        else {
            const int ch = 2 * node + seg;     // seg=1 -> 2n+1, seg=2 -> 2n+2
            v = (ch >= 255) ? embed[(size_t)values[ch] * HID + idx]
                            : h[(size_t)ch * HID + idx];
        }
        cat[cc][e] = v;
    }
    __syncthreads();
    // phase 1: child matvecs (parallel children, split-K=2)
    {
        const float4* wq = (const float4*)Wq + o;
        const float4* c4 = (const float4*)cat[cid] + kh * 96;
        float acc = 0.f;
#pragma unroll 16
        for (int k4 = 0; k4 < 96; k4++) {
            const float4 w = wq[(size_t)(kh * 96 + k4) * 256];
            const float4 cc = c4[k4];
            acc += w.x * cc.x + w.y * cc.y + w.z * cc.z + w.w * cc.w;
        }
        part[g][o] = acc;
    }
    __syncthreads();
    // combine children + stage parent cat (one barrier)
    if (t < 512) {
        const int c = t >> 8;
        pcat[256 + (c << 8) + o] = part[c][o] + part[c + 2][o] + bpar[o];
    } else if (t < 768) {
        const int idx = t & 255;
        pcat[idx] = embed[(size_t)values[i] * HID + idx];
    }
    __syncthreads();
    // phase 2: parent matvec, split-K=4
    {
        const float4* wq = (const float4*)Wq + o;
        const float4* c4 = (const float4*)pcat + g * 48;
        float acc = 0.f;
#pragma unroll 16
        for (int k4 = 0; k4 < 48; k4++) {
            const float4 w = wq[(size_t)(g * 48 + k4) * 256];
            const float4 cc = c4[k4];
            acc += w.x * cc.x + w.y * cc.y + w.z * cc.z + w.w * cc.w;
        }
        part[g][o] = acc;
    }
    __syncthreads();
    if (t < 256)
        h[(size_t)i * HID + t] = part[0][t] + part[1][t] + part[2][t] + part[3][t] + bpar[t];
}

// ---------------- final: nodes 1,2 (parallel) + node 0 + head + z ------------
__global__ __launch_bounds__(1024)
void enc_final(const float* __restrict__ embed, const int* __restrict__ values,
               const float* __restrict__ Wq, const float* __restrict__ bpar,
               const float* __restrict__ h,
               const float* __restrict__ Wq_mu, const float* __restrict__ bmu,
               const float* __restrict__ Wq_lv, const float* __restrict__ blv,
               const float* __restrict__ eps,
               float* __restrict__ out, float* __restrict__ z) {
    const int t = threadIdx.x;
    const int o = t & 255;
    const int g = t >> 8;
    const int cid = g & 1, kh = g >> 1;
    __shared__ __align__(16) float cat[2][768];
    __shared__ float part[4][256];
    __shared__ __align__(16) float pcat[768];
    __shared__ __align__(16) float r0[256];
    __shared__ float mu_s[128], lv_s[128];

    // stage cats for nodes 1 and 2 (children 3,4 / 5,6 all in h)
    for (int q = t; q < 1536; q += 1024) {
        const int cc = (q >= 768);
        const int e = q - cc * 768;
        const int node = 1 + cc;
        const int seg = e >> 8, idx = e & 255;
        cat[cc][e] = (seg == 0) ? embed[(size_t)values[node] * HID + idx]
                                : h[(size_t)(2 * node + seg) * HID + idx];
    }
    __syncthreads();
    {
        const float4* wq = (const float4*)Wq + o;
        const float4* c4 = (const float4*)cat[cid] + kh * 96;
        float acc = 0.f;
#pragma unroll 16
        for (int k4 = 0; k4 < 96; k4++) {
            const float4 w = wq[(size_t)(kh * 96 + k4) * 256];
            const float4 cc = c4[k4];
            acc += w.x * cc.x + w.y * cc.y + w.z * cc.z + w.w * cc.w;
        }
        part[g][o] = acc;
    }
    __syncthreads();
    if (t < 512) {
        const int c = t >> 8;
        pcat[256 + (c << 8) + o] = part[c][o] + part[c + 2][o] + bpar[o];
    } else if (t < 768) {
        const int idx = t & 255;
        pcat[idx] = embed[(size_t)values[0] * HID + idx];
    }
    __syncthreads();
    {
        const float4* wq = (const float4*)Wq + o;
        const float4* c4 = (const float4*)pcat + g * 48;
        float acc = 0.f;
#pragma unroll 16
        for (int k4 = 0; k4 < 48; k4++) {
            const float4 w = wq[(size_t)(g * 48 + k4) * 256];
            const float4 cc = c4[k4];
            acc += w.x * cc.x + w.y * cc.y + w.z * cc.z + w.w * cc.w;
        }
        part[g][o] = acc;
    }
    __syncthreads();
    if (t < 256)
        r0[t] = part[0][t] + part[1][t] + part[2][t] + part[3][t] + bpar[t];
    __syncthreads();
    // head: 256 virtual rows (0-127 mu, 128-255 lv), split-K=4
    {
        const int r = o & 127;
        const float4* wqh = (const float4*)(o < 128 ? Wq_mu : Wq_lv) + r;
        const float4* r4 = (const float4*)r0 + g * 16;
        float acc = 0.f;
#pragma unroll 16
        for (int k4 = 0; k4 < 16; k4++) {
            const float4 w = wqh[(size_t)(g * 16 + k4) * 128];
            const float4 cc = r4[k4];
            acc += w.x * cc.x + w.y * cc.y + w.z * cc.z + w.w * cc.w;
        }
        part[g][o] = acc;
    }
    __syncthreads();
    if (t < 256) {
        const int r = t & 127;
        float v = part[0][t] + part[1][t] + part[2][t] + part[3][t];
        if (t < 128) { v += bmu[r]; out[(size_t)NSTEP * VOC + r] = v;       mu_s[r] = v; }
        else         { v += blv[r]; out[(size_t)NSTEP * VOC + 128 + r] = v; lv_s[r] = v; }
    }
    __syncthreads();
    if (t < 128) z[t] = mu_s[t] + eps[t] * expf(0.5f * lv_s[t]);
}

// ---------------- sequential decoder recurrence (unchanged, known-good) ------
__global__ __launch_bounds__(512, 2)
void recur_kernel(const float* W1, const float* b1,
                  const float* W2, const float* b2,
                  const float* Wcomb, const float* bcomb,
                  const float* z,
                  float* Hrec, int* rowflag) {
    const int t = threadIdx.x;
    const int o = t >> 1;                  // 0..255
    const int hk = t & 1;
    __shared__ __align__(16) float stack_s[64 * 128];   // 32 KB
    __shared__ __align__(16) float hmid_s[256];

    // resident weights (pointers not __restrict + global store in loop ->
    // compiler cannot rematerialize; weights stay in VGPRs)
    float4 w1r[16];
#pragma unroll
    for (int j = 0; j < 16; j++)
        w1r[j] = *(const float4*)(W1 + (size_t)o * 128 + hk * 64 + 4 * j);
    float4 wcr[32];
#pragma unroll
    for (int j = 0; j < 32; j++)
        wcr[j] = *(const float4*)(Wcomb + (size_t)o * 256 + hk * 128 + 4 * j);

    const float b1o = b1[o];
    const float bco = bcomb[o];
    const float b20 = b2[0];
    const int l64 = t & 63;
    const float4 w2q = *(const float4*)(W2 + 4 * l64);

    if (t < 128) stack_s[t] = z[t];
    int sp = 1, op = 0;
    unsigned long long pm0 = 0ULL, pm1 = 0ULL;
    __syncthreads();

    for (int step = 0; step < NSTEP; step++) {
        if (sp <= 0) break;
        const int idx = sp - 1;

        // mv1: hmid = lrelu(W1 @ node + b1), split-K=2 (even/odd lanes)
        const float* np = stack_s + idx * 128 + hk * 64;
        float a = 0.f;
#pragma unroll
        for (int j = 0; j < 16; j++) {
            const float4 v = *(const float4*)(np + 4 * j);
            a += w1r[j].x * v.x + w1r[j].y * v.y + w1r[j].z * v.z + w1r[j].w * v.w;
        }
        a += __shfl_xor(a, 1);
        if (hk == 0) {
            float pre = a + b1o;
            pre = pre > 0.f ? pre : 0.2f * pre;
            hmid_s[o] = pre;
            Hrec[(size_t)op * HID + o] = pre;   // remat-blocker + record
        }
        __syncthreads();                         // b1: hmid visible

        // c0 decision dot: every wave redundantly (identical result)
        const float4 hq = *(const float4*)(hmid_s + 4 * l64);
        float c = w2q.x * hq.x + w2q.y * hq.y + w2q.z * hq.z + w2q.w * hq.w;
        c += __shfl_xor(c, 1);  c += __shfl_xor(c, 2);  c += __shfl_xor(c, 4);
        c += __shfl_xor(c, 8);  c += __shfl_xor(c, 16); c += __shfl_xor(c, 32);
        const bool par = ((c + b20) > 0.f) && (sp <= 63);

        if (par) {
            // mv2: push = Wcomb @ hmid + bcomb (parents only)
            const float* hp = hmid_s + hk * 128;
            float s = 0.f;
#pragma unroll
            for (int j = 0; j < 32; j++) {
                const float4 v = *(const float4*)(hp + 4 * j);
                s += wcr[j].x * v.x + wcr[j].y * v.y + wcr[j].z * v.z + wcr[j].w * v.w;
            }
            s += __shfl_xor(s, 1);
            if (hk == 0)                           // ll -> idx, rl -> idx+1
                stack_s[(idx + (o >> 7)) * 128 + (o & 127)] = s + bco;
            if (op < 64) pm0 |= (1ULL << op); else pm1 |= (1ULL << (op - 64));
            sp += 1;
        } else {
            sp -= 1;
        }
        op++;
        __syncthreads();                         // b2: stack update visible
    }

    if (t < 128) {
        int f = -1;
        if (t < op) f = (t < 64) ? (int)((pm0 >> t) & 1) : (int)((pm1 >> (t - 64)) & 1);
        rowflag[t] = f;
    }
}

// ---------------- Co1 = Hrec @ W2[1:].T + b2[1:] (packed, coalesced) ---------
__global__ __launch_bounds__(256)
void co1_kernel(const float* __restrict__ Hrec, const float* __restrict__ Wq_w2,
                const float* __restrict__ b2, float* __restrict__ Co1) {
    const int r = blockIdx.x;              // 0..127
    const int c = threadIdx.x;             // 0..255
    __shared__ __align__(16) float hs[256];
    hs[c] = Hrec[(size_t)r * HID + c];
    __syncthreads();
    float acc = b2[1 + c];
    const float4* wq = (const float4*)Wq_w2 + c;
    const float4* h4 = (const float4*)hs;
#pragma unroll 8
    for (int k4 = 0; k4 < 64; k4++) {
        const float4 a = wq[k4 * 256];
        const float4 hv = h4[k4];
        acc += a.x * hv.x + a.y * hv.y + a.z * hv.z + a.w * hv.w;
    }
    Co1[(size_t)r * HID + c] = acc;
}

// ---------------- batched vocab matvecs (unchanged, known-good) --------------
__global__ __launch_bounds__(256, 1)
void value_kernel(const float* __restrict__ Co1, const int* __restrict__ rowflag,
                  const float* __restrict__ Wl, const float* __restrict__ bl,
                  const float* __restrict__ Wp, const float* __restrict__ bp,
                  float* __restrict__ out) {
    const int m = blockIdx.y;              // 0 = leaf (Wl) + zero rows, 1 = parent (Wp)
    const int t = threadIdx.x;
    const int v = blockIdx.x * 256 + t;    // 125 blocks x 256 = 32000
    __shared__ int list_s[128];
    __shared__ int zlist_s[128];
    __shared__ int nn_s, nz_s;
    if (t == 0) {
        int n = 0, znum = 0;
        for (int r = 0; r < 128; r++) {
            const int f = rowflag[r];
            if (f == m) list_s[n++] = r;
            else if (m == 0 && f == -1) zlist_s[znum++] = r;
        }
        nn_s = n; nz_s = znum;
    }
    __syncthreads();
    const int n = nn_s;
    const float* Wx = m ? Wp : Wl;
    const float* bx = m ? bp : bl;
    const float bv = bx[v];
    const float4* w4 = (const float4*)(Wx + (size_t)v * HID);

    for (int rc = 0; rc < n; rc += 32) {
        const int nr = min(32, n - rc);
        float acc[32];
#pragma unroll
        for (int rr = 0; rr < 32; rr++) acc[rr] = 0.f;
        for (int kc = 0; kc < 4; kc++) {
            float4 w[16];
#pragma unroll
            for (int i = 0; i < 16; i++) w[i] = w4[kc * 16 + i];
            for (int rr = 0; rr < nr; rr++) {
                const int row = __builtin_amdgcn_readfirstlane(list_s[rc + rr]);
                const float* cp = Co1 + (size_t)row * HID + kc * 64;
                float s = 0.f;
#pragma unroll
                for (int i = 0; i < 16; i++) {
                    const float4 c4 = *(const float4*)(cp + 4 * i);
                    s += w[i].x * c4.x + w[i].y * c4.y + w[i].z * c4.z + w[i].w * c4.w;
                }
                acc[rr] += s;
            }
        }
        for (int rr = 0; rr < nr; rr++) {
            const int row = __builtin_amdgcn_readfirstlane(list_s[rc + rr]);
            out[(size_t)row * VOC + v] = acc[rr] + bv;
        }
    }
    if (m == 0) {
        const int nz = nz_s;
        for (int i = 0; i < nz; i++) {
            const int row = __builtin_amdgcn_readfirstlane(zlist_s[i]);
            out[(size_t)row * VOC + v] = 0.f;
        }
    }
}

extern "C" void kernel_launch(void* const* d_in, const int* in_sizes, int n_in,
                              void* d_out, int out_size, void* d_ws, size_t ws_size,
                              hipStream_t stream) {
    const float* embed = (const float*)d_in[0];
    const float* Wpar  = (const float*)d_in[1];
    const float* bpar  = (const float*)d_in[2];
    const float* Wmu   = (const float*)d_in[3];
    const float* bmu   = (const float*)d_in[4];
    const float* Wlv   = (const float*)d_in[5];
    const float* blv   = (const float*)d_in[6];
    const float* W1    = (const float*)d_in[7];
    const float* b1    = (const float*)d_in[8];
    const float* W2    = (const float*)d_in[9];
    const float* b2    = (const float*)d_in[10];
    const float* Wl    = (const float*)d_in[11];
    const float* bl    = (const float*)d_in[12];
    const float* Wp    = (const float*)d_in[13];
    const float* bp    = (const float*)d_in[14];
    const float* eps   = (const float*)d_in[15];
    const int*  values = (const int*)d_in[16];

    float* ws = (float*)d_ws;
    float* h       = ws;                    // 255*256 = 65280
    float* z       = ws + 65280;            // 128
    float* Wcomb   = ws + 65408;            // 65536
    float* bcomb   = ws + 130944;           // 256
    float* Hrec    = ws + 131200;           // 32768
    float* Co1     = ws + 163968;           // 32768
    int*   rowflag = (int*)(ws + 196736);   // 128
    float* Wq_par  = ws + 196864;           // 196608
    float* Wq_mu   = ws + 393472;           // 32768
    float* Wq_lv   = ws + 426240;           // 32768
    float* Wq_w2   = ws + 459008;           // 65536
    float* out = (float*)d_out;

    // prep: wcomb (256) + Wpar pack (96) + mu/lv pack (32) + W2 pack (32)
    prep_kernel<<<416, 512, 0, stream>>>(Wp, W2, b2, bp, Wpar, Wmu, Wlv,
                                         Wcomb, bcomb, Wq_par, Wq_mu, Wq_lv, Wq_w2);

    // encoder: fused level pairs (6,7) -> (4,5) -> (2,3) -> (0,1)+head
    enc2<<<64, 1024, 0, stream>>>(embed, values, Wq_par, bpar, h, 63);
    enc2<<<16, 1024, 0, stream>>>(embed, values, Wq_par, bpar, h, 15);
    enc2<<< 4, 1024, 0, stream>>>(embed, values, Wq_par, bpar, h,  3);
    enc_final<<<1, 1024, 0, stream>>>(embed, values, Wq_par, bpar, h,
                                      Wq_mu, bmu, Wq_lv, blv, eps, out, z);

    recur_kernel<<<1, 512, 0, stream>>>(W1, b1, W2, b2, Wcomb, bcomb, z, Hrec, rowflag);

    co1_kernel<<<128, 256, 0, stream>>>(Hrec, Wq_w2, b2, Co1);
    value_kernel<<<dim3(125, 2), 256, 0, stream>>>(Co1, rowflag, Wl, bl, Wp, bp, out);
}